// Round 1
// baseline (1996.334 us; speedup 1.0000x reference)
//
#include <hip/hip_runtime.h>
#include <hip/hip_bf16.h>

// Problem constants (fixed by the reference)
#define NN 100000
#define NE 6400000
#define F_IN 50
#define H1 30
#define H2 25

// ---------------------------------------------------------------------------
// 1) in-degree count at dst (self-loop handled as +1 later)
__global__ __launch_bounds__(256) void k_count(const int* __restrict__ dst,
                                               int* __restrict__ deg) {
    int i = blockIdx.x * 256 + threadIdx.x;
    if (i < NE) atomicAdd(&deg[dst[i]], 1);
}

// 2) dinv = rsqrt(deg+1)
__global__ __launch_bounds__(256) void k_dinv(const int* __restrict__ deg,
                                              float* __restrict__ dinv) {
    int i = blockIdx.x * 256 + threadIdx.x;
    if (i < NN) dinv[i] = rsqrtf((float)(deg[i] + 1));
}

// 3) h1 = x @ W1 ; agg1 = dinv^2 * h1  (self-loop init, no memset needed)
__global__ __launch_bounds__(256) void k_gemm1(const float* __restrict__ x,
                                               const float* __restrict__ W1,
                                               const float* __restrict__ dinv,
                                               float* __restrict__ h1,
                                               float* __restrict__ agg1) {
    __shared__ float Ws[F_IN * H1];
    for (int i = threadIdx.x; i < F_IN * H1; i += 256) Ws[i] = W1[i];
    __syncthreads();
    int n = blockIdx.x * 256 + threadIdx.x;
    if (n >= NN) return;
    float xr[F_IN];
#pragma unroll
    for (int k = 0; k < F_IN; ++k) xr[k] = x[n * F_IN + k];
    float d = dinv[n];
    float d2 = d * d;
    for (int j = 0; j < H1; ++j) {
        float acc = 0.f;
#pragma unroll
        for (int k = 0; k < F_IN; ++k) acc = fmaf(xr[k], Ws[k * H1 + j], acc);
        h1[n * H1 + j]   = acc;
        agg1[n * H1 + j] = d2 * acc;
    }
}

// 4) edge scatter, layer 1: 32 lanes per edge, lanes f<H1 active
__global__ __launch_bounds__(256) void k_edge1(const int* __restrict__ src,
                                               const int* __restrict__ dst,
                                               const float* __restrict__ dinv,
                                               const float* __restrict__ h1,
                                               float* __restrict__ agg1) {
    int t = blockIdx.x * 256 + threadIdx.x;          // < NE*32 = 204.8M, fits int
    int e = t >> 5;
    int f = t & 31;
    if (e >= NE || f >= H1) return;
    int s = src[e];
    int d = dst[e];
    float w = dinv[s] * dinv[d];
    atomicAdd(&agg1[d * H1 + f], w * h1[s * H1 + f]);
}

// 5) a = relu(agg1 + b1); t2 = a @ W2; out = dinv^2 * t2 + b2 (self loop + bias)
__global__ __launch_bounds__(256) void k_gemm2(const float* __restrict__ agg1,
                                               const float* __restrict__ W2,
                                               const float* __restrict__ b1,
                                               const float* __restrict__ b2,
                                               const float* __restrict__ dinv,
                                               float* __restrict__ t2,
                                               float* __restrict__ out) {
    __shared__ float Ws[H1 * H2];
    __shared__ float b1s[H1];
    __shared__ float b2s[H2];
    for (int i = threadIdx.x; i < H1 * H2; i += 256) Ws[i] = W2[i];
    if (threadIdx.x < H1) b1s[threadIdx.x] = b1[threadIdx.x];
    if (threadIdx.x < H2) b2s[threadIdx.x] = b2[threadIdx.x];
    __syncthreads();
    int n = blockIdx.x * 256 + threadIdx.x;
    if (n >= NN) return;
    float a[H1];
#pragma unroll
    for (int k = 0; k < H1; ++k)
        a[k] = fmaxf(agg1[n * H1 + k] + b1s[k], 0.f);
    float d = dinv[n];
    float d2 = d * d;
    for (int j = 0; j < H2; ++j) {
        float acc = 0.f;
#pragma unroll
        for (int k = 0; k < H1; ++k) acc = fmaf(a[k], Ws[k * H2 + j], acc);
        t2[n * H2 + j]  = acc;
        out[n * H2 + j] = d2 * acc + b2s[j];
    }
}

// 6) edge scatter, layer 2: into d_out directly
__global__ __launch_bounds__(256) void k_edge2(const int* __restrict__ src,
                                               const int* __restrict__ dst,
                                               const float* __restrict__ dinv,
                                               const float* __restrict__ t2,
                                               float* __restrict__ out) {
    int t = blockIdx.x * 256 + threadIdx.x;
    int e = t >> 5;
    int f = t & 31;
    if (e >= NE || f >= H2) return;
    int s = src[e];
    int d = dst[e];
    float w = dinv[s] * dinv[d];
    atomicAdd(&out[d * H2 + f], w * t2[s * H2 + f]);
}

extern "C" void kernel_launch(void* const* d_in, const int* in_sizes, int n_in,
                              void* d_out, int out_size, void* d_ws, size_t ws_size,
                              hipStream_t stream) {
    const float* x   = (const float*)d_in[0];
    const int*   ei  = (const int*)d_in[1];   // [2, NE]: row 0 = src, row 1 = dst
    const float* W1  = (const float*)d_in[2];
    const float* b1  = (const float*)d_in[3];
    const float* W2  = (const float*)d_in[4];
    const float* b2  = (const float*)d_in[5];
    float*       out = (float*)d_out;

    const int* src = ei;
    const int* dst = ei + NE;

    // workspace layout (bytes), 128B-aligned chunks
    char* ws = (char*)d_ws;
    int*   deg  = (int*)  (ws + 0);            // 400,000 B
    float* dinv = (float*)(ws + 400128);       // 400,000 B
    float* h1   = (float*)(ws + 800256);       // 12,000,000 B
    float* agg1 = (float*)(ws + 12800256);     // 12,000,000 B
    float* t2   = (float*)(ws + 24800256);     // 10,000,000 B
    // total ~34.8 MB

    hipMemsetAsync(deg, 0, (size_t)NN * sizeof(int), stream);

    k_count<<<(NE + 255) / 256, 256, 0, stream>>>(dst, deg);
    k_dinv<<<(NN + 255) / 256, 256, 0, stream>>>(deg, dinv);
    k_gemm1<<<(NN + 255) / 256, 256, 0, stream>>>(x, W1, dinv, h1, agg1);

    // 32 lanes per edge
    {
        long long threads = (long long)NE * 32;
        int blocks = (int)((threads + 255) / 256);
        k_edge1<<<blocks, 256, 0, stream>>>(src, dst, dinv, h1, agg1);
    }

    k_gemm2<<<(NN + 255) / 256, 256, 0, stream>>>(agg1, W2, b1, b2, dinv, t2, out);

    {
        long long threads = (long long)NE * 32;
        int blocks = (int)((threads + 255) / 256);
        k_edge2<<<blocks, 256, 0, stream>>>(src, dst, dinv, t2, out);
    }
}

// Round 2
// 1387.077 us; speedup vs baseline: 1.4392x; 1.4392x over previous
//
#include <hip/hip_runtime.h>
#include <hip/hip_bf16.h>

// Problem constants (fixed by the reference)
#define NN 100000
#define NE 6400000
#define F_IN 50
#define H1 30
#define H2 25

// ---------------------------------------------------------------------------
// Common: degree count + dinv
__global__ __launch_bounds__(256) void k_count(const int* __restrict__ dst,
                                               int* __restrict__ deg) {
    int i = blockIdx.x * 256 + threadIdx.x;
    if (i < NE) atomicAdd(&deg[dst[i]], 1);
}

__global__ __launch_bounds__(256) void k_dinv(const int* __restrict__ deg,
                                              float* __restrict__ dinv) {
    int i = blockIdx.x * 256 + threadIdx.x;
    if (i < NN) dinv[i] = rsqrtf((float)(deg[i] + 1));
}

// h1 = x @ W1 ; optionally (fallback path) agg1 = dinv^2 * h1
__global__ __launch_bounds__(256) void k_gemm1(const float* __restrict__ x,
                                               const float* __restrict__ W1,
                                               const float* __restrict__ dinv,
                                               float* __restrict__ h1,
                                               float* __restrict__ agg1) {
    __shared__ float Ws[F_IN * H1];
    for (int i = threadIdx.x; i < F_IN * H1; i += 256) Ws[i] = W1[i];
    __syncthreads();
    int n = blockIdx.x * 256 + threadIdx.x;
    if (n >= NN) return;
    float xr[F_IN];
#pragma unroll
    for (int k = 0; k < F_IN; ++k) xr[k] = x[n * F_IN + k];
    float d = dinv[n];
    float d2 = d * d;
    for (int j = 0; j < H1; ++j) {
        float acc = 0.f;
#pragma unroll
        for (int k = 0; k < F_IN; ++k) acc = fmaf(xr[k], Ws[k * H1 + j], acc);
        h1[n * H1 + j] = acc;
        if (agg1) agg1[n * H1 + j] = d2 * acc;
    }
}

// ---------------------------------------------------------------------------
// CSR path
// ---------------------------------------------------------------------------

// exclusive scan of deg[NN] -> rowptr[NN+1], plus cursor copy
__global__ __launch_bounds__(1024) void k_scan(const int* __restrict__ deg,
                                               int* __restrict__ rowptr,
                                               int* __restrict__ cursor) {
    __shared__ int part[1024];
    const int CH = (NN + 1023) / 1024;  // 98
    int t = threadIdx.x;
    int lo = t * CH;
    int hi = lo + CH; if (hi > NN) hi = NN;
    int s = 0;
    if (lo < NN) for (int i = lo; i < hi; ++i) s += deg[i];
    part[t] = s;
    __syncthreads();
    // inclusive scan (Hillis-Steele)
    for (int off = 1; off < 1024; off <<= 1) {
        int v = (t >= off) ? part[t - off] : 0;
        __syncthreads();
        part[t] += v;
        __syncthreads();
    }
    int run = (t == 0) ? 0 : part[t - 1];  // exclusive base for this chunk
    if (lo < NN) {
        for (int i = lo; i < hi; ++i) {
            rowptr[i] = run;
            cursor[i] = run;
            run += deg[i];
        }
    }
    if (t == 1023) rowptr[NN] = part[1023];
}

// bucket edges by dst: ebuf[rowptr[d] ...] = src ids
__global__ __launch_bounds__(256) void k_scatter(const int* __restrict__ src,
                                                 const int* __restrict__ dst,
                                                 int* __restrict__ cursor,
                                                 int* __restrict__ ebuf) {
    int e = blockIdx.x * 256 + threadIdx.x;
    if (e >= NE) return;
    int d = dst[e];
    int p = atomicAdd(&cursor[d], 1);
    ebuf[p] = src[e];
}

// Layer-1 aggregation fused with bias+ReLU+GEMM2 -> t2
// one 32-lane group per node (8 nodes / 256-block); NN % 8 == 0
__global__ __launch_bounds__(256) void k_agg1(const int* __restrict__ rowptr,
                                              const int* __restrict__ ebuf,
                                              const float* __restrict__ dinv,
                                              const float* __restrict__ h1,
                                              const float* __restrict__ W2,
                                              const float* __restrict__ b1,
                                              float* __restrict__ t2) {
    __shared__ float W2s[H1 * H2];
    __shared__ float b1s[H1];
    __shared__ float a_lds[8][32];
    for (int i = threadIdx.x; i < H1 * H2; i += 256) W2s[i] = W2[i];
    if (threadIdx.x < H1) b1s[threadIdx.x] = b1[threadIdx.x];
    __syncthreads();

    int g = threadIdx.x >> 5;
    int lane = threadIdx.x & 31;
    int n = blockIdx.x * 8 + g;

    if (n < NN) {
        int f = (lane < H1) ? lane : 0;  // clamp to stay in-row
        int beg = rowptr[n], end = rowptr[n + 1];
        float acc = 0.f;
        for (int base = beg; base < end; base += 32) {
            int idx = base + lane;
            bool act = idx < end;
            int   sv = act ? ebuf[idx] : 0;
            float wv = act ? dinv[sv] : 0.f;
#pragma unroll
            for (int i = 0; i < 32; ++i) {
                int   s = __shfl(sv, i, 32);
                float w = __shfl(wv, i, 32);
                acc = fmaf(w, h1[s * H1 + f], acc);
            }
        }
        float dn = dinv[n];
        float val = dn * acc + dn * dn * h1[n * H1 + f];
        a_lds[g][lane] = fmaxf(val + b1s[f], 0.f);
    }
    __syncthreads();
    if (n < NN && lane < H2) {
        float t = 0.f;
#pragma unroll
        for (int k = 0; k < H1; ++k) t = fmaf(a_lds[g][k], W2s[k * H2 + lane], t);
        t2[n * H2 + lane] = t;
    }
}

// Layer-2 aggregation -> out (+b2)
__global__ __launch_bounds__(256) void k_agg2(const int* __restrict__ rowptr,
                                              const int* __restrict__ ebuf,
                                              const float* __restrict__ dinv,
                                              const float* __restrict__ t2,
                                              const float* __restrict__ b2,
                                              float* __restrict__ out) {
    __shared__ float b2s[H2];
    if (threadIdx.x < H2) b2s[threadIdx.x] = b2[threadIdx.x];
    __syncthreads();

    int g = threadIdx.x >> 5;
    int lane = threadIdx.x & 31;
    int n = blockIdx.x * 8 + g;
    if (n >= NN) return;

    int f = (lane < H2) ? lane : 0;
    int beg = rowptr[n], end = rowptr[n + 1];
    float acc = 0.f;
    for (int base = beg; base < end; base += 32) {
        int idx = base + lane;
        bool act = idx < end;
        int   sv = act ? ebuf[idx] : 0;
        float wv = act ? dinv[sv] : 0.f;
#pragma unroll
        for (int i = 0; i < 32; ++i) {
            int   s = __shfl(sv, i, 32);
            float w = __shfl(wv, i, 32);
            acc = fmaf(w, t2[s * H2 + f], acc);
        }
    }
    float dn = dinv[n];
    if (lane < H2)
        out[n * H2 + lane] = dn * acc + dn * dn * t2[n * H2 + f] + b2s[lane];
}

// ---------------------------------------------------------------------------
// Fallback path (round-1 proven): fp32 atomic scatter
// ---------------------------------------------------------------------------
__global__ __launch_bounds__(256) void k_edge1(const int* __restrict__ src,
                                               const int* __restrict__ dst,
                                               const float* __restrict__ dinv,
                                               const float* __restrict__ h1,
                                               float* __restrict__ agg1) {
    int t = blockIdx.x * 256 + threadIdx.x;
    int e = t >> 5;
    int f = t & 31;
    if (e >= NE || f >= H1) return;
    int s = src[e];
    int d = dst[e];
    float w = dinv[s] * dinv[d];
    atomicAdd(&agg1[d * H1 + f], w * h1[s * H1 + f]);
}

__global__ __launch_bounds__(256) void k_gemm2(const float* __restrict__ agg1,
                                               const float* __restrict__ W2,
                                               const float* __restrict__ b1,
                                               const float* __restrict__ b2,
                                               const float* __restrict__ dinv,
                                               float* __restrict__ t2,
                                               float* __restrict__ out) {
    __shared__ float Ws[H1 * H2];
    __shared__ float b1s[H1];
    __shared__ float b2s[H2];
    for (int i = threadIdx.x; i < H1 * H2; i += 256) Ws[i] = W2[i];
    if (threadIdx.x < H1) b1s[threadIdx.x] = b1[threadIdx.x];
    if (threadIdx.x < H2) b2s[threadIdx.x] = b2[threadIdx.x];
    __syncthreads();
    int n = blockIdx.x * 256 + threadIdx.x;
    if (n >= NN) return;
    float a[H1];
#pragma unroll
    for (int k = 0; k < H1; ++k)
        a[k] = fmaxf(agg1[n * H1 + k] + b1s[k], 0.f);
    float d = dinv[n];
    float d2 = d * d;
    for (int j = 0; j < H2; ++j) {
        float acc = 0.f;
#pragma unroll
        for (int k = 0; k < H1; ++k) acc = fmaf(a[k], Ws[k * H2 + j], acc);
        t2[n * H2 + j]  = acc;
        out[n * H2 + j] = d2 * acc + b2s[j];
    }
}

__global__ __launch_bounds__(256) void k_edge2(const int* __restrict__ src,
                                               const int* __restrict__ dst,
                                               const float* __restrict__ dinv,
                                               const float* __restrict__ t2,
                                               float* __restrict__ out) {
    int t = blockIdx.x * 256 + threadIdx.x;
    int e = t >> 5;
    int f = t & 31;
    if (e >= NE || f >= H2) return;
    int s = src[e];
    int d = dst[e];
    float w = dinv[s] * dinv[d];
    atomicAdd(&out[d * H2 + f], w * t2[s * H2 + f]);
}

// ---------------------------------------------------------------------------
extern "C" void kernel_launch(void* const* d_in, const int* in_sizes, int n_in,
                              void* d_out, int out_size, void* d_ws, size_t ws_size,
                              hipStream_t stream) {
    const float* x   = (const float*)d_in[0];
    const int*   ei  = (const int*)d_in[1];   // [2, NE]: row 0 = src, row 1 = dst
    const float* W1  = (const float*)d_in[2];
    const float* b1  = (const float*)d_in[3];
    const float* W2  = (const float*)d_in[4];
    const float* b2  = (const float*)d_in[5];
    float*       out = (float*)d_out;

    const int* src = ei;
    const int* dst = ei + NE;

    char* ws = (char*)d_ws;

    const size_t NEED_CSR = 49200768;  // see layout below

    if (ws_size >= NEED_CSR) {
        // ---- CSR gather path ----
        int*   deg    = (int*)  (ws + 0);           //   400,000 B
        int*   rowptr = (int*)  (ws + 400128);      //   400,004 B
        int*   cursor = (int*)  (ws + 800256);      //   400,000 B
        float* dinv   = (float*)(ws + 1200384);     //   400,000 B
        float* h1     = (float*)(ws + 1600512);     // 12,000,000 B
        float* t2     = (float*)(ws + 13600640);    // 10,000,000 B
        int*   ebuf   = (int*)  (ws + 23600768);    // 25,600,000 B -> 49,200,768

        hipMemsetAsync(deg, 0, (size_t)NN * sizeof(int), stream);
        k_count<<<(NE + 255) / 256, 256, 0, stream>>>(dst, deg);
        k_dinv<<<(NN + 255) / 256, 256, 0, stream>>>(deg, dinv);
        k_scan<<<1, 1024, 0, stream>>>(deg, rowptr, cursor);
        k_scatter<<<(NE + 255) / 256, 256, 0, stream>>>(src, dst, cursor, ebuf);
        k_gemm1<<<(NN + 255) / 256, 256, 0, stream>>>(x, W1, dinv, h1, nullptr);
        k_agg1<<<(NN + 7) / 8, 256, 0, stream>>>(rowptr, ebuf, dinv, h1, W2, b1, t2);
        k_agg2<<<(NN + 7) / 8, 256, 0, stream>>>(rowptr, ebuf, dinv, t2, b2, out);
    } else {
        // ---- fallback: fp32 atomic scatter (round-1 proven) ----
        int*   deg  = (int*)  (ws + 0);
        float* dinv = (float*)(ws + 400128);
        float* h1   = (float*)(ws + 800256);
        float* agg1 = (float*)(ws + 12800256);
        float* t2   = (float*)(ws + 24800256);

        hipMemsetAsync(deg, 0, (size_t)NN * sizeof(int), stream);
        k_count<<<(NE + 255) / 256, 256, 0, stream>>>(dst, deg);
        k_dinv<<<(NN + 255) / 256, 256, 0, stream>>>(deg, dinv);
        k_gemm1<<<(NN + 255) / 256, 256, 0, stream>>>(x, W1, dinv, h1, agg1);
        {
            long long threads = (long long)NE * 32;
            int blocks = (int)((threads + 255) / 256);
            k_edge1<<<blocks, 256, 0, stream>>>(src, dst, dinv, h1, agg1);
        }
        k_gemm2<<<(NN + 255) / 256, 256, 0, stream>>>(agg1, W2, b1, b2, dinv, t2, out);
        {
            long long threads = (long long)NE * 32;
            int blocks = (int)((threads + 255) / 256);
            k_edge2<<<blocks, 256, 0, stream>>>(src, dst, dinv, t2, out);
        }
    }
}